// Round 7
// baseline (146.640 us; speedup 1.0000x reference)
//
#include <hip/hip_runtime.h>

// MaskedTimeAttention: B=32, En=512, De=64, D_en=D_de=U=128
// ws: att_en (32*512*128 f32 = 8 MB) | att_de_sc (32*64*128 f32 = 1 MB)
// XCD plan: every block touching batch b has bid%8 == b%8 (8 XCDs), so
// att_en[b]/en_seq[b] stay in one XCD's L2 from producer to consumer.

#define TWO_LOG2E 2.8853900817779268f
#define LOG2E     1.4426950408889634f

__device__ __forceinline__ float fexp2(float x){
#if __has_builtin(__builtin_amdgcn_exp2f)
  return __builtin_amdgcn_exp2f(x);
#else
  float r; asm("v_exp_f32 %0, %1" : "=v"(r) : "v"(x)); return r;
#endif
}
__device__ __forceinline__ float frcp(float x){
#if __has_builtin(__builtin_amdgcn_rcpf)
  return __builtin_amdgcn_rcpf(x);
#else
  float r; asm("v_rcp_f32 %0, %1" : "=v"(r) : "v"(x)); return r;
#endif
}

// ---------------- Kernel A: att_en = (en*mask)@w_en ; att_de_sc = (de@w_de)*2log2e ----
// 288 blocks x 512 thr, 64 output rows each. LDS 64KB -> 2 blocks/CU (16 waves, 50%).
// en: bi<256: b=bi&31, j=bi>>5 -> rows b*512+j*64   (bi%8 == b%8)
// de: bi>=256: b=bi-256   -> rows b*64               ((256+b)%8 == b%8)
__global__ __launch_bounds__(512) void k_gemms(
    const float* __restrict__ en_seq, const float* __restrict__ de_seq,
    const float* __restrict__ w_en, const float* __restrict__ w_de,
    const int* __restrict__ mask,
    float* __restrict__ att_en, float* __restrict__ att_de_sc)
{
  __shared__ __align__(16) float Ws[64*128];   // 32 KB (half of K per phase)
  __shared__ __align__(16) float As[64*128];   // 32 KB (64 rows)
  const int bi = blockIdx.x, tid = threadIdx.x;
  const float* A; const float* W; float* O; int row0; bool masked;
  if (bi < 256) { int b = bi & 31, j = bi >> 5;
                  A = en_seq; W = w_en; O = att_en;    row0 = b*512 + j*64; masked = true; }
  else          { int b = bi - 256;
                  A = de_seq; W = w_de; O = att_de_sc; row0 = b*64;         masked = false; }

  const float4* A4 = (const float4*)(A + row0*128);
  float4* As4 = (float4*)As;
#pragma unroll
  for (int i = 0; i < 4; ++i) As4[tid + 512*i] = A4[tid + 512*i];

  const int c0 = (tid & 31) * 4;   // output col
  const int r0 = (tid >> 5) * 4;   // output row within 64-row tile
  float acc[4][4] = {};

  for (int ph = 0; ph < 2; ++ph) {
    if (ph) __syncthreads();                     // phase-0 compute done before overwrite
    const float4* W4 = (const float4*)(W + ph*64*128);
    float4* Ws4 = (float4*)Ws;
#pragma unroll
    for (int i = 0; i < 4; ++i) Ws4[tid + 512*i] = W4[tid + 512*i];
    __syncthreads();
    for (int k = 0; k < 64; k += 4) {
      const int kg = ph*64 + k;
      float4 av[4], wv[4];
#pragma unroll
      for (int r = 0; r < 4; ++r) av[r] = *(const float4*)&As[(r0+r)*128 + kg];  // broadcast
#pragma unroll
      for (int kk = 0; kk < 4; ++kk) wv[kk] = *(const float4*)&Ws[(k+kk)*128 + c0];
#pragma unroll
      for (int r = 0; r < 4; ++r) {
        const float* ar = (const float*)&av[r];
#pragma unroll
        for (int kk = 0; kk < 4; ++kk) {
          acc[r][0] = fmaf(ar[kk], wv[kk].x, acc[r][0]);
          acc[r][1] = fmaf(ar[kk], wv[kk].y, acc[r][1]);
          acc[r][2] = fmaf(ar[kk], wv[kk].z, acc[r][2]);
          acc[r][3] = fmaf(ar[kk], wv[kk].w, acc[r][3]);
        }
      }
    }
  }
#pragma unroll
  for (int r = 0; r < 4; ++r) {
    const int row = row0 + r0 + r;
    // (en*m)@W == m*(en@W); de-path folds the 2*log2e exp2 prescale instead.
    const float m = masked ? (float)mask[row] : TWO_LOG2E;
    float4 o = { acc[r][0]*m, acc[r][1]*m, acc[r][2]*m, acc[r][3]*m };
    *(float4*)&O[row*128 + c0] = o;
  }
}

// ---------------- Kernel B: fused tanh-score + softmax + weighted sum ----------------
// 256 blocks (b = bid&31 -> XCD b%8; dg = bid>>5), 1024 thr = 16 waves.
// u-SPLIT: waves 0-7 accumulate u in [0,64), waves 8-15 u in [64,128) -> two partial-mu
// arrays (alphA/alphB) combined at softmax. Doubles resident waves: 16/CU (50% cap).
// Pass-1 lane map: dP = l&7 (d), er = l>>3 (e-row); wave wl covers tile rows wl*8+er.
// Tile: [64][128] f32, quad-XOR swizzle q^=(row&7) -> conflict-free b128 read/write.
// LDS 72320 B -> 1 block/CU (grid == 256 == #CUs anyway).
__global__ __launch_bounds__(1024) void k_att(
    const float* __restrict__ att_en, const float* __restrict__ att_de_sc,
    const float* __restrict__ nu, const int* __restrict__ mask,
    const float* __restrict__ en_seq, const float* __restrict__ de_seq,
    float* __restrict__ out)
{
  __shared__ __align__(16) float smem[18080];
  float* const tile  = smem;            // 8192 f32 (64x128 swizzled); later: part
  float* const alphA = smem + 8192;     // 8 x 520 (stride 520: 520%32==8 -> <=2-way)
  float* const alphB = smem + 12352;    // 8 x 520
  float* const m_s   = smem + 16512;    // 512
  float* const adC   = smem + 17024;    // 8 x 132 (pad: 8-lane multicast conflict-free)
  float* const part  = smem;            // alias of tile (pass-2 partials, 8192 f32)

  const int tid = threadIdx.x;
  const int l = tid & 63, w = tid >> 6;        // w in [0,16)
  const int wl = w & 7, uh = w >> 3;           // wave-group, u-half
  const int b = blockIdx.x & 31, dg = blockIdx.x >> 5;

  // ---- staging: att_de rows (padded), mask ----
  if (tid < 256) {
    const int row = tid >> 5, q = tid & 31;
    *(float4*)&adC[row*132 + q*4] =
        *(const float4*)&att_de_sc[(b*64 + dg*8 + row)*128 + q*4];
  }
  if (tid >= 512) m_s[tid - 512] = (float)mask[b*512 + tid - 512];

  // S_nu = sum(nu) (tanh*nu sum = S_nu - 2*sum(rcp*nu))
  float snu = nu[l] + nu[l + 64];
#pragma unroll
  for (int off = 32; off > 0; off >>= 1) snu += __shfl_xor(snu, off, 64);
  const float S_nu = snu;

  float4 rg[2];
  const float4* AE4 = (const float4*)(att_en + (size_t)b * (512*128));
#define SLOAD(t) { _Pragma("unroll") for (int i_=0;i_<2;++i_) rg[i_] = AE4[(t)*2048 + tid + 1024*i_]; }
#define SWRITE() { _Pragma("unroll") for (int i_=0;i_<2;++i_){ const int f4i_ = tid + 1024*i_; \
                   const int row_ = f4i_>>5, q_ = f4i_&31; \
                   *(float4*)&tile[row_*128 + ((q_ ^ (row_&7))<<2)] = rg[i_]; } }
  SLOAD(0);
  SWRITE();
  __syncthreads();

  // ---- pass 1: partial mu = sum over this wave's u-half of rcp(e^{2x}+1)*nu ----
  const int dP = l & 7, er = l >> 3;
  const int r  = wl*8 + er;                // tile row; r&7 == er
  const float* adrow = adC + dP*132 + uh*64;
  const float* nuh   = nu + uh*64;
  float* const alphX = uh ? alphB : alphA;
  for (int t = 0; t < 8; ++t) {
    if (t < 7) SLOAD(t+1);                 // loads in flight across compute
    float a0=0.f, a1=0.f, a2=0.f, a3=0.f;
#pragma unroll
    for (int uc = 0; uc < 16; ++uc) {
      const int q = (uh*16 + uc) ^ er;
      float4 ae = *(const float4*)&tile[r*128 + (q<<2)];   // 8-lane multicast, conflict-free
      float4 ad = *(const float4*)&adrow[uc<<2];
      float4 nv = *(const float4*)&nuh[uc<<2];             // wave-uniform -> scalar
      float e0 = fexp2(fmaf(ae.x, TWO_LOG2E, ad.x));
      float e1 = fexp2(fmaf(ae.y, TWO_LOG2E, ad.y));
      float e2 = fexp2(fmaf(ae.z, TWO_LOG2E, ad.z));
      float e3 = fexp2(fmaf(ae.w, TWO_LOG2E, ad.w));
      a0 = fmaf(frcp(e0 + 1.f), nv.x, a0);
      a1 = fmaf(frcp(e1 + 1.f), nv.y, a1);
      a2 = fmaf(frcp(e2 + 1.f), nv.z, a2);
      a3 = fmaf(frcp(e3 + 1.f), nv.w, a3);
    }
    alphX[dP*520 + t*64 + wl*8 + er] = (a0+a1)+(a2+a3);
    __syncthreads();                       // all reads of tile done
    if (t < 7) { SWRITE(); __syncthreads(); }
  }

  // ---- wave softmax (waves 0-7; wave w owns d = dg*8+w) ----
  // scrambled bias: mask[b, d*8 + e/64] -> m_s[dg*64 + w*8 + t]
  if (w < 8) {
    float v[8]; float mx = -3.0e38f;
#pragma unroll
    for (int t = 0; t < 8; ++t) {
      v[t] = S_nu - 2.f*(alphA[w*520 + t*64 + l] + alphB[w*520 + t*64 + l])
           + (m_s[dg*64 + w*8 + t] - 1.f) * 10000.f;
      mx = fmaxf(mx, v[t]);
    }
#pragma unroll
    for (int off = 32; off > 0; off >>= 1) mx = fmaxf(mx, __shfl_xor(mx, off, 64));
    float s = 0.f, p[8];
#pragma unroll
    for (int t = 0; t < 8; ++t) { p[t] = fexp2((v[t]-mx)*LOG2E); s += p[t]; }
#pragma unroll
    for (int off = 32; off > 0; off >>= 1) s += __shfl_xor(s, off, 64);
    const float inv = frcp(s);
#pragma unroll
    for (int t = 0; t < 8; ++t)            // fold en-mask: sum_e a*(m*en) = (a*m)*en
      alphA[w*520 + t*64 + l] = p[t]*inv*m_s[t*64 + l];
  }
  __syncthreads();

  // ---- pass 2 (waves 0-7): sum_en = alphas @ en_seq; f0=(l&15)*8, e-sub=l>>4 ----
  if (w < 8) {
    const int f0 = (l & 15) * 8, es = l >> 4;
    float acc2[8][8] = {};
    const float* enB = en_seq + (size_t)b * (512*128);
    for (int it = 0; it < 16; ++it) {
      const int e = w*64 + it*4 + es;
      float4 ev0 = *(const float4*)&enB[e*128 + f0];
      float4 ev1 = *(const float4*)&enB[e*128 + f0 + 4];
#pragma unroll
      for (int dd = 0; dd < 8; ++dd) {
        const float a = alphA[dd*520 + e];   // broadcast to 16 lanes
        acc2[dd][0] = fmaf(a, ev0.x, acc2[dd][0]);
        acc2[dd][1] = fmaf(a, ev0.y, acc2[dd][1]);
        acc2[dd][2] = fmaf(a, ev0.z, acc2[dd][2]);
        acc2[dd][3] = fmaf(a, ev0.w, acc2[dd][3]);
        acc2[dd][4] = fmaf(a, ev1.x, acc2[dd][4]);
        acc2[dd][5] = fmaf(a, ev1.y, acc2[dd][5]);
        acc2[dd][6] = fmaf(a, ev1.z, acc2[dd][6]);
        acc2[dd][7] = fmaf(a, ev1.w, acc2[dd][7]);
      }
    }
#pragma unroll
    for (int dd = 0; dd < 8; ++dd)
#pragma unroll
      for (int j = 0; j < 8; ++j) {
        acc2[dd][j] += __shfl_xor(acc2[dd][j], 16, 64);
        acc2[dd][j] += __shfl_xor(acc2[dd][j], 32, 64);
      }
    if (l < 16) {
#pragma unroll
      for (int dd = 0; dd < 8; ++dd) {
        float4 t0 = { acc2[dd][0], acc2[dd][1], acc2[dd][2], acc2[dd][3] };
        float4 t1 = { acc2[dd][4], acc2[dd][5], acc2[dd][6], acc2[dd][7] };
        *(float4*)&part[(w*8 + dd)*128 + f0]     = t0;  // part aliases tile (pass 1 done)
        *(float4*)&part[(w*8 + dd)*128 + f0 + 4] = t1;
      }
    }
  }
  __syncthreads();

  // ---- cross-wave reduce + output (de_seq copy fused) ----
  if (tid < 256) {
    const int dd = tid >> 5, fq = (tid & 31) * 4;
    float4 s2 = {0.f, 0.f, 0.f, 0.f};
#pragma unroll
    for (int ww = 0; ww < 8; ++ww) {
      float4 pv = *(const float4*)&part[(ww*8 + dd)*128 + fq];
      s2.x += pv.x; s2.y += pv.y; s2.z += pv.z; s2.w += pv.w;
    }
    const int drow = b*64 + dg*8 + dd;
    *(float4*)&out[drow*256 + fq]       = *(const float4*)&de_seq[drow*128 + fq];
    *(float4*)&out[drow*256 + 128 + fq] = s2;
  }
}

extern "C" void kernel_launch(void* const* d_in, const int* in_sizes, int n_in,
                              void* d_out, int out_size, void* d_ws, size_t ws_size,
                              hipStream_t stream) {
  const float* en_seq = (const float*)d_in[0];   // (32,512,128)
  const float* de_seq = (const float*)d_in[1];   // (32,64,128)
  const int*   mask   = (const int*)  d_in[2];   // (32,512)
  const float* w_en   = (const float*)d_in[3];   // (128,128)
  const float* w_de   = (const float*)d_in[4];   // (128,128)
  const float* nu     = (const float*)d_in[5];   // (128,1)
  float* out = (float*)d_out;                    // (32,64,256)

  float* att_en    = (float*)d_ws;               // 32*512*128 f32
  float* att_de_sc = att_en + 32*512*128;        // 32*64*128  f32

  k_gemms<<<288, 512, 0, stream>>>(en_seq, de_seq, w_en, w_de, mask, att_en, att_de_sc);
  k_att<<<256, 1024, 0, stream>>>(att_en, att_de_sc, nu, mask, en_seq, de_seq, out);
}